// Round 8
// baseline (858.683 us; speedup 1.0000x reference)
//
#include <hip/hip_runtime.h>
#include <math.h>

#define NN 16384
#define KK 16
#define RPW 2                       // rows per scan wave
#define SCAN_WAVES 4
#define RPB (SCAN_WAVES * RPW)      // 8 rows per block

typedef float f32x4 __attribute__((ext_vector_type(4)));

// ---------- pack nodes into SoA float4 {x,y,z,sq} (reference arithmetic) ----
__global__ void prep_kernel(const float* __restrict__ nodes,
                            float4* __restrict__ pts) {
#pragma clang fp contract(off)
    const int i = blockIdx.x * blockDim.x + threadIdx.x;
    if (i < NN) {
        const float x = nodes[3 * i + 0];
        const float y = nodes[3 * i + 1];
        const float z = nodes[3 * i + 2];
        pts[i] = make_float4(x, y, z, (x * x + y * y) + z * z);
    }
}

// Verified distributed-sorted-list insert (identical machinery to r1-r6).
__device__ __forceinline__ bool lexless(float da, int ia, float db, int ib) {
    return (da < db) || ((da == db) && (ia < ib));
}

__device__ __forceinline__ void insert_tile(bool rough, float d2, int j,
                                            float& ld, int& li,
                                            float& td, int& ti, float& td2u,
                                            int lane) {
#pragma clang fp contract(off)
    if (!__any(rough)) return;
    float dist = INFINITY;
    if (rough) dist = sqrtf(fmaxf(d2, 0.0f));   // IEEE sqrt, matches reference
    bool done = false;
    while (true) {
        const bool pass = (!done) && rough && lexless(dist, j, td, ti);
        const unsigned long long m = __ballot(pass);
        if (m == 0ull) break;
        const int src = __ffsll(m) - 1;
        const float dc = __shfl(dist, src);
        const int   ic = __shfl(j, src);
        if (lane == src) done = true;
        const bool gt = lexless(dc, ic, ld, li);
        const unsigned long long gm = __ballot(gt);
        const int p = __ffsll(gm) - 1;
        const float pd = __shfl_up(ld, 1);
        const int   pi = __shfl_up(li, 1);
        if (gt) {
            if (lane == p) { ld = dc; li = ic; }
            else           { ld = pd; li = pi; }
        }
        td = __shfl(ld, 16);
        ti = __shfl(li, 16);
        td2u = td * td * 1.000001f;   // conservative d2-domain screen bound
    }
}

// ---------- main kernel: 4 scan waves (2 rows each) + 1 zero/ones wave ------
// INSTRUMENTED: scan waves repeat the full scan `passes` times (identical
// deterministic result each pass; opaque seed blocks compiler CSE). This
// surfaces knn_main in the rocprof top-5 so we finally see its counters.
__global__ __launch_bounds__(320) void knn_main(const float4* __restrict__ pts,
                                                float* __restrict__ out,
                                                int passes) {
#pragma clang fp contract(off)
    const int lane = threadIdx.x & 63;
    const int wid  = threadIdx.x >> 6;
    const int rowBase = blockIdx.x * RPB;
    __shared__ int nb[RPB][16];

    if (wid == SCAN_WAVES) {
        // Zero wave: NT-stream zeros for this block's 8 rows (512 KB).
        f32x4* ob = (f32x4*)(out + (size_t)rowBase * NN);
        const f32x4 z4 = {0.f, 0.f, 0.f, 0.f};
#pragma unroll 8
        for (int k = 0; k < RPB * (NN / 4) / 64; ++k)
            __builtin_nontemporal_store(z4, ob + k * 64 + lane);
        // Drain so this wave's later 1.0 stores are ordered after the zeros.
        asm volatile("s_waitcnt vmcnt(0)" ::: "memory");
    } else {
        const int rowA = rowBase + wid * RPW;
        const float4 pA = pts[rowA];
        const float4 pB = pts[rowA + 1];
        const float xA = pA.x, yA = pA.y, zA = pA.z, sA = pA.w;
        const float xB = pB.x, yB = pB.y, zB = pB.z, sB = pB.w;

        float ldA, tdA, t2A, ldB, tdB, t2B;
        int liA, tiA, liB, tiB;

        for (int pass = 0; pass < passes; ++pass) {
            // Opaque seed: compiler cannot prove passes identical -> no CSE.
            float seed = INFINITY;
            asm volatile("" : "+v"(seed));
            ldA = seed; liA = 0x7fffffff;
            tdA = seed; tiA = 0x7fffffff; t2A = seed;
            ldB = seed; liB = 0x7fffffff;
            tdB = seed; tiB = 0x7fffffff; t2B = seed;

            float4 q0 = pts[lane];
            float4 q1 = pts[64 + lane];
            float4 q2 = pts[128 + lane];
            float4 q3 = pts[192 + lane];

            for (int t = 0; t < NN / 256; ++t) {
                const int base = t * 256;
                const int nxt = (t + 1 < NN / 256) ? base + 256 : base;
                const float4 n0 = pts[nxt + lane];
                const float4 n1 = pts[nxt + 64 + lane];
                const float4 n2 = pts[nxt + 128 + lane];
                const float4 n3 = pts[nxt + 192 + lane];

                // Reference arithmetic: fma-chain dot, un-contracted d2.
                const float dA0 = (sA + q0.w) - 2.0f * fmaf(zA, q0.z, fmaf(yA, q0.y, xA * q0.x));
                const float dA1 = (sA + q1.w) - 2.0f * fmaf(zA, q1.z, fmaf(yA, q1.y, xA * q1.x));
                const float dA2 = (sA + q2.w) - 2.0f * fmaf(zA, q2.z, fmaf(yA, q2.y, xA * q2.x));
                const float dA3 = (sA + q3.w) - 2.0f * fmaf(zA, q3.z, fmaf(yA, q3.y, xA * q3.x));
                const float dB0 = (sB + q0.w) - 2.0f * fmaf(zB, q0.z, fmaf(yB, q0.y, xB * q0.x));
                const float dB1 = (sB + q1.w) - 2.0f * fmaf(zB, q1.z, fmaf(yB, q1.y, xB * q1.x));
                const float dB2 = (sB + q2.w) - 2.0f * fmaf(zB, q2.z, fmaf(yB, q2.y, xB * q2.x));
                const float dB3 = (sB + q3.w) - 2.0f * fmaf(zB, q3.z, fmaf(yB, q3.y, xB * q3.x));

                const float mnA = fminf(fminf(dA0, dA1), fminf(dA2, dA3));
                const float mnB = fminf(fminf(dB0, dB1), fminf(dB2, dB3));
                if (__any((mnA <= t2A) || (mnB <= t2B))) {
                    insert_tile(dA0 <= t2A, dA0, base + lane,       ldA, liA, tdA, tiA, t2A, lane);
                    insert_tile(dA1 <= t2A, dA1, base + 64 + lane,  ldA, liA, tdA, tiA, t2A, lane);
                    insert_tile(dA2 <= t2A, dA2, base + 128 + lane, ldA, liA, tdA, tiA, t2A, lane);
                    insert_tile(dA3 <= t2A, dA3, base + 192 + lane, ldA, liA, tdA, tiA, t2A, lane);
                    insert_tile(dB0 <= t2B, dB0, base + lane,       ldB, liB, tdB, tiB, t2B, lane);
                    insert_tile(dB1 <= t2B, dB1, base + 64 + lane,  ldB, liB, tdB, tiB, t2B, lane);
                    insert_tile(dB2 <= t2B, dB2, base + 128 + lane, ldB, liB, tdB, tiB, t2B, lane);
                    insert_tile(dB3 <= t2B, dB3, base + 192 + lane, ldB, liB, tdB, tiB, t2B, lane);
                }
                q0 = n0; q1 = n1; q2 = n2; q3 = n3;
            }
        }

        // Deposit neighbor indices (lanes 1..16 hold them in sorted order).
        if (lane >= 1 && lane <= KK) {
            nb[wid * RPW + 0][lane - 1] = liA;
            nb[wid * RPW + 1][lane - 1] = liB;
        }
    }

    __syncthreads();

    // Zero wave writes all 128 ones: same-wave ordering after its vmcnt(0)
    // drain guarantees the 1.0s land after the zeros.
    if (wid == SCAN_WAVES) {
#pragma unroll
        for (int m = lane; m < RPB * 16; m += 64) {
            const int r = m >> 4;
            out[(size_t)(rowBase + r) * NN + nb[r][m & 15]] = 1.0f;
        }
    }
}

extern "C" void kernel_launch(void* const* d_in, const int* in_sizes, int n_in,
                              void* d_out, int out_size, void* d_ws, size_t ws_size,
                              hipStream_t stream) {
    const float* nodes = (const float*)d_in[0];
    float* out = (float*)d_out;
    (void)in_sizes; (void)n_in; (void)out_size; (void)ws_size;
    float4* pts = (float4*)d_ws;    // 256 KB scratch

    hipLaunchKernelGGL(prep_kernel, dim3(NN / 256), dim3(256), 0, stream,
                       nodes, pts);
    hipLaunchKernelGGL(knn_main, dim3(NN / RPB), dim3(320), 0, stream,
                       pts, out, 3 /* instrumentation: 3x scan repeat */);
}

// Round 10
// 608.390 us; speedup vs baseline: 1.4114x; 1.4114x over previous
//
#include <hip/hip_runtime.h>
#include <math.h>

#define NN 16384
#define KK 16
#define RPW 2                       // rows per scan wave
#define SCAN_WAVES 4
#define RPB (SCAN_WAVES * RPW)      // 8 rows per block

typedef float f32x4 __attribute__((ext_vector_type(4)));
typedef unsigned long long u64;

// ---------- pack nodes into SoA float4 {x,y,z,sq} (reference arithmetic) ----
__global__ void prep_kernel(const float* __restrict__ nodes,
                            float4* __restrict__ pts) {
#pragma clang fp contract(off)
    const int i = blockIdx.x * blockDim.x + threadIdx.x;
    if (i < NN) {
        const float x = nodes[3 * i + 0];
        const float y = nodes[3 * i + 1];
        const float z = nodes[3 * i + 2];
        pts[i] = make_float4(x, y, z, (x * x + y * y) + z * z);
    }
}

__device__ __forceinline__ bool lexless(float da, int ia, float db, int ib) {
    return (da < db) || ((da == db) && (ia < ib));
}

// Consume-loop: one round per passing candidate. Explicit `used` flags mark
// consumption (NOT an INF sentinel: INF<=INF is true and t2 starts at INF —
// that was r9's infinite loop). One ballot per entry round; ONE sqrt per
// consumed candidate; exact lex-(dist,idx) check before the verified insert.
__device__ __forceinline__ void consume_row(float c0, float c1, float c2, float c3,
                                            int base, int lane,
                                            float& ld, int& li,
                                            float& td, int& ti, float& t2) {
#pragma clang fp contract(off)
    bool u0 = false, u1 = false, u2 = false, u3 = false;
    while (true) {
        const bool p0 = !u0 && (c0 <= t2), p1 = !u1 && (c1 <= t2);
        const bool p2 = !u2 && (c2 <= t2), p3 = !u3 && (c3 <= t2);
        const u64 m = __ballot(p0 || p1 || p2 || p3);
        if (m == 0ull) break;
        const int src = __ffsll(m) - 1;
        // src lane's first passing candidate
        const float dsel = p0 ? c0 : (p1 ? c1 : (p2 ? c2 : c3));
        const int   ksel = p0 ? 0  : (p1 ? 1  : (p2 ? 2  : 3 ));
        const float d2c = __shfl(dsel, src);
        const int   ic  = __shfl(base + ksel * 64 + lane, src);
        if (lane == src) {   // mark consumed (guaranteed progress each round)
            if (p0) u0 = true; else if (p1) u1 = true;
            else if (p2) u2 = true; else u3 = true;
        }
        const float distc = sqrtf(fmaxf(d2c, 0.0f));   // IEEE, matches reference
        if (lexless(distc, ic, td, ti)) {
            const bool gt = lexless(distc, ic, ld, li);
            const u64 gm = __ballot(gt);
            const int p = __ffsll(gm) - 1;
            const float pd = __shfl_up(ld, 1);
            const int   pi = __shfl_up(li, 1);
            if (gt) {
                if (lane == p) { ld = distc; li = ic; }
                else           { ld = pd;    li = pi; }
            }
            td = __shfl(ld, 16);
            ti = __shfl(li, 16);
            t2 = td * td * 1.000001f;   // conservative d2-domain screen bound
        }
    }
}

// ---------- main kernel: 4 scan waves (2 rows each) + 1 zero/ones wave ------
__global__ __launch_bounds__(320) void knn_main(const float4* __restrict__ pts,
                                                float* __restrict__ out) {
#pragma clang fp contract(off)
    const int lane = threadIdx.x & 63;
    const int wid  = threadIdx.x >> 6;
    const int rowBase = blockIdx.x * RPB;
    __shared__ int nb[RPB][16];

    if (wid == SCAN_WAVES) {
        // Zero wave: NT-stream zeros for this block's 8 rows (512 KB).
        f32x4* ob = (f32x4*)(out + (size_t)rowBase * NN);
        const f32x4 z4 = {0.f, 0.f, 0.f, 0.f};
#pragma unroll 8
        for (int k = 0; k < RPB * (NN / 4) / 64; ++k)
            __builtin_nontemporal_store(z4, ob + k * 64 + lane);
        // Drain so this wave's later 1.0 stores are ordered after the zeros.
        asm volatile("s_waitcnt vmcnt(0)" ::: "memory");
    } else {
        const int rowA = rowBase + wid * RPW;
        const float4 pA = pts[rowA];
        const float4 pB = pts[rowA + 1];
        const float xA = pA.x, yA = pA.y, zA = pA.z, sA = pA.w;
        const float xB = pB.x, yB = pB.y, zB = pB.z, sB = pB.w;

        float ldA = INFINITY; int liA = 0x7fffffff;
        float tdA = INFINITY; int tiA = 0x7fffffff; float t2A = INFINITY;
        float ldB = INFINITY; int liB = 0x7fffffff;
        float tdB = INFINITY; int tiB = 0x7fffffff; float t2B = INFINITY;

        float4 q0 = pts[lane];
        float4 q1 = pts[64 + lane];
        float4 q2 = pts[128 + lane];
        float4 q3 = pts[192 + lane];

#pragma unroll 2
        for (int t = 0; t < NN / 256; ++t) {
            const int base = t * 256;
            const int nxt = (t + 1 < NN / 256) ? base + 256 : base;
            const float4 n0 = pts[nxt + lane];
            const float4 n1 = pts[nxt + 64 + lane];
            const float4 n2 = pts[nxt + 128 + lane];
            const float4 n3 = pts[nxt + 192 + lane];

            // Reference arithmetic: fma-chain dot, un-contracted d2.
            const float dA0 = (sA + q0.w) - 2.0f * fmaf(zA, q0.z, fmaf(yA, q0.y, xA * q0.x));
            const float dA1 = (sA + q1.w) - 2.0f * fmaf(zA, q1.z, fmaf(yA, q1.y, xA * q1.x));
            const float dA2 = (sA + q2.w) - 2.0f * fmaf(zA, q2.z, fmaf(yA, q2.y, xA * q2.x));
            const float dA3 = (sA + q3.w) - 2.0f * fmaf(zA, q3.z, fmaf(yA, q3.y, xA * q3.x));
            const float dB0 = (sB + q0.w) - 2.0f * fmaf(zB, q0.z, fmaf(yB, q0.y, xB * q0.x));
            const float dB1 = (sB + q1.w) - 2.0f * fmaf(zB, q1.z, fmaf(yB, q1.y, xB * q1.x));
            const float dB2 = (sB + q2.w) - 2.0f * fmaf(zB, q2.z, fmaf(yB, q2.y, xB * q2.x));
            const float dB3 = (sB + q3.w) - 2.0f * fmaf(zB, q3.z, fmaf(yB, q3.y, xB * q3.x));

            const bool aA = (dA0 <= t2A) || (dA1 <= t2A) || (dA2 <= t2A) || (dA3 <= t2A);
            const bool aB = (dB0 <= t2B) || (dB1 <= t2B) || (dB2 <= t2B) || (dB3 <= t2B);
            if (__any(aA || aB)) {
                consume_row(dA0, dA1, dA2, dA3, base, lane, ldA, liA, tdA, tiA, t2A);
                consume_row(dB0, dB1, dB2, dB3, base, lane, ldB, liB, tdB, tiB, t2B);
            }
            q0 = n0; q1 = n1; q2 = n2; q3 = n3;
        }

        // Deposit neighbor indices (lanes 1..16 hold them in sorted order).
        if (lane >= 1 && lane <= KK) {
            nb[wid * RPW + 0][lane - 1] = liA;
            nb[wid * RPW + 1][lane - 1] = liB;
        }
    }

    __syncthreads();

    // Zero wave writes all 128 ones: same-wave ordering after its vmcnt(0)
    // drain guarantees the 1.0s land after the zeros.
    if (wid == SCAN_WAVES) {
#pragma unroll
        for (int m = lane; m < RPB * 16; m += 64) {
            const int r = m >> 4;
            out[(size_t)(rowBase + r) * NN + nb[r][m & 15]] = 1.0f;
        }
    }
}

extern "C" void kernel_launch(void* const* d_in, const int* in_sizes, int n_in,
                              void* d_out, int out_size, void* d_ws, size_t ws_size,
                              hipStream_t stream) {
    const float* nodes = (const float*)d_in[0];
    float* out = (float*)d_out;
    (void)in_sizes; (void)n_in; (void)out_size; (void)ws_size;
    float4* pts = (float4*)d_ws;    // 256 KB scratch

    hipLaunchKernelGGL(prep_kernel, dim3(NN / 256), dim3(256), 0, stream,
                       nodes, pts);
    hipLaunchKernelGGL(knn_main, dim3(NN / RPB), dim3(320), 0, stream,
                       pts, out);
}

// Round 11
// 424.017 us; speedup vs baseline: 2.0251x; 1.4348x over previous
//
#include <hip/hip_runtime.h>
#include <math.h>

#define NN 16384
#define KK 16
#define LIST 20     // top-20 by (d2,idx); slack 3 over K+1 covers sqrt-tie inversions
#define RPW 2                       // rows per scan wave
#define SCAN_WAVES 4
#define RPB (SCAN_WAVES * RPW)      // 8 rows per block

typedef float f32x4 __attribute__((ext_vector_type(4)));
typedef unsigned long long u64;

// ---------- pack nodes into SoA float4 {x,y,z,sq} (reference arithmetic) ----
__global__ void prep_kernel(const float* __restrict__ nodes,
                            float4* __restrict__ pts) {
#pragma clang fp contract(off)
    const int i = blockIdx.x * blockDim.x + threadIdx.x;
    if (i < NN) {
        const float x = nodes[3 * i + 0];
        const float y = nodes[3 * i + 1];
        const float z = nodes[3 * i + 2];
        pts[i] = make_float4(x, y, z, (x * x + y * y) + z * z);
    }
}

// Uniform-lane broadcast via v_readlane (scalar path, NO ds_bpermute).
__device__ __forceinline__ float bcastf(float v, int l) {
    return __int_as_float(__builtin_amdgcn_readlane(__float_as_int(v), l));
}
__device__ __forceinline__ int bcasti(int v, int l) {
    return __builtin_amdgcn_readlane(v, l);
}

// d2-domain distributed top-20 insert, one 64-candidate slot per call.
// Same r1-verified invariant (done-flags, threshold-from-worst-lane, shfl_up
// shift) but: no sqrt, broadcasts via readlane, candidate idx recovered from
// scalar arithmetic. Exactly ONE bpermute-latency wait per round (the shift).
__device__ __forceinline__ void ins_d2(float d2raw, int jbase, int lane,
                                       float& ld, int& li,
                                       float& tdd, int& tii) {
#pragma clang fp contract(off)
    const int jl = jbase + lane;
    bool done = false;
    while (true) {
        // Conservative superset of clamped-(d2,idx) < (tdd,tii): raw<=clamped,
        // and tdd>0 always (only self has d2<=0), so no spurious inserts.
        const bool pass = !done &&
            ((d2raw < tdd) || ((d2raw == tdd) && (jl < tii)));
        const u64 m = __ballot(pass);
        if (m == 0ull) break;
        const int src = (int)(__ffsll(m) - 1);
        const float dc = fmaxf(bcastf(d2raw, src), 0.0f);   // clamped domain
        const int   ic = jbase + src;                       // no data movement
        if (lane == src) done = true;
        const bool gt = (dc < ld) || ((dc == ld) && (ic < li));
        const u64 gm = __ballot(gt);
        const int p = (int)(__ffsll(gm) - 1);
        const float pd = __shfl_up(ld, 1);                  // the one bpermute pair
        const int   pi = __shfl_up(li, 1);
        if (gt) {
            if (lane == p) { ld = dc; li = ic; }
            else           { ld = pd; li = pi; }
        }
        tdd = bcastf(ld, LIST - 1);                         // readlane, no LDS
        tii = bcasti(li, LIST - 1);
    }
}

// ---------- main kernel: 4 scan waves (2 rows each) + 1 zero/ones wave ------
__global__ __launch_bounds__(320) void knn_main(const float4* __restrict__ pts,
                                                float* __restrict__ out) {
#pragma clang fp contract(off)
    const int lane = threadIdx.x & 63;
    const int wid  = threadIdx.x >> 6;
    const int rowBase = blockIdx.x * RPB;
    __shared__ int nb[RPB][16];

    if (wid == SCAN_WAVES) {
        // Zero wave: NT-stream zeros for this block's 8 rows (512 KB).
        f32x4* ob = (f32x4*)(out + (size_t)rowBase * NN);
        const f32x4 z4 = {0.f, 0.f, 0.f, 0.f};
#pragma unroll 8
        for (int k = 0; k < RPB * (NN / 4) / 64; ++k)
            __builtin_nontemporal_store(z4, ob + k * 64 + lane);
        // Drain so this wave's later 1.0 stores are ordered after the zeros.
        asm volatile("s_waitcnt vmcnt(0)" ::: "memory");
    } else {
        const int rowA = rowBase + wid * RPW;
        const float4 pA = pts[rowA];
        const float4 pB = pts[rowA + 1];
        const float xA = pA.x, yA = pA.y, zA = pA.z, sA = pA.w;
        const float xB = pB.x, yB = pB.y, zB = pB.z, sB = pB.w;

        float ldA = INFINITY; int liA = 0x7fffffff;   // my list slot (lanes 0..19)
        float tdA = INFINITY; int tiA = 0x7fffffff;   // lane-19 (worst kept)
        float ldB = INFINITY; int liB = 0x7fffffff;
        float tdB = INFINITY; int tiB = 0x7fffffff;

        float4 q0 = pts[lane];
        float4 q1 = pts[64 + lane];
        float4 q2 = pts[128 + lane];
        float4 q3 = pts[192 + lane];

        for (int t = 0; t < NN / 256; ++t) {
            const int base = t * 256;
            const int nxt = (t + 1 < NN / 256) ? base + 256 : base;
            const float4 n0 = pts[nxt + lane];
            const float4 n1 = pts[nxt + 64 + lane];
            const float4 n2 = pts[nxt + 128 + lane];
            const float4 n3 = pts[nxt + 192 + lane];

            // Reference arithmetic: fma-chain dot, un-contracted d2.
            const float dA0 = (sA + q0.w) - 2.0f * fmaf(zA, q0.z, fmaf(yA, q0.y, xA * q0.x));
            const float dA1 = (sA + q1.w) - 2.0f * fmaf(zA, q1.z, fmaf(yA, q1.y, xA * q1.x));
            const float dA2 = (sA + q2.w) - 2.0f * fmaf(zA, q2.z, fmaf(yA, q2.y, xA * q2.x));
            const float dA3 = (sA + q3.w) - 2.0f * fmaf(zA, q3.z, fmaf(yA, q3.y, xA * q3.x));
            const float dB0 = (sB + q0.w) - 2.0f * fmaf(zB, q0.z, fmaf(yB, q0.y, xB * q0.x));
            const float dB1 = (sB + q1.w) - 2.0f * fmaf(zB, q1.z, fmaf(yB, q1.y, xB * q1.x));
            const float dB2 = (sB + q2.w) - 2.0f * fmaf(zB, q2.z, fmaf(yB, q2.y, xB * q2.x));
            const float dB3 = (sB + q3.w) - 2.0f * fmaf(zB, q3.z, fmaf(yB, q3.y, xB * q3.x));

            // Decoupled per-row gates (f32-only, <= keeps the d2==threshold
            // idx-tie case; spurious fires are harmless).
            const bool fA = (fminf(fminf(dA0, dA1), fminf(dA2, dA3)) <= tdA);
            const bool fB = (fminf(fminf(dB0, dB1), fminf(dB2, dB3)) <= tdB);
            if (__any(fA)) {
                ins_d2(dA0, base,       lane, ldA, liA, tdA, tiA);
                ins_d2(dA1, base + 64,  lane, ldA, liA, tdA, tiA);
                ins_d2(dA2, base + 128, lane, ldA, liA, tdA, tiA);
                ins_d2(dA3, base + 192, lane, ldA, liA, tdA, tiA);
            }
            if (__any(fB)) {
                ins_d2(dB0, base,       lane, ldB, liB, tdB, tiB);
                ins_d2(dB1, base + 64,  lane, ldB, liB, tdB, tiB);
                ins_d2(dB2, base + 128, lane, ldB, liB, tdB, tiB);
                ins_d2(dB3, base + 192, lane, ldB, liB, tdB, tiB);
            }
            q0 = n0; q1 = n1; q2 = n2; q3 = n3;
        }

        // ---- exact (dist, idx) rank among the top-20 (r7-verified pattern,
        // via readlane instead of LDS). Rank 0 = self; ranks 1..16 = neighbors.
        {
            const float dfA = sqrtf(ldA);   // IEEE sqrt of clamped d2, as ref
            const float dfB = sqrtf(ldB);
            int rkA = 0, rkB = 0;
#pragma unroll
            for (int mq = 0; mq < LIST; ++mq) {
                const float dmA = bcastf(dfA, mq);
                const int   imA = bcasti(liA, mq);
                rkA += ((dmA < dfA) || ((dmA == dfA) && (imA < liA))) ? 1 : 0;
                const float dmB = bcastf(dfB, mq);
                const int   imB = bcasti(liB, mq);
                rkB += ((dmB < dfB) || ((dmB == dfB) && (imB < liB))) ? 1 : 0;
            }
            if (lane < LIST && rkA >= 1 && rkA <= KK)
                nb[wid * RPW + 0][rkA - 1] = liA;
            if (lane < LIST && rkB >= 1 && rkB <= KK)
                nb[wid * RPW + 1][rkB - 1] = liB;
        }
    }

    __syncthreads();

    // Zero wave writes all 128 ones: same-wave ordering after its vmcnt(0)
    // drain guarantees the 1.0s land after the zeros.
    if (wid == SCAN_WAVES) {
#pragma unroll
        for (int m = lane; m < RPB * 16; m += 64) {
            const int r = m >> 4;
            out[(size_t)(rowBase + r) * NN + nb[r][m & 15]] = 1.0f;
        }
    }
}

extern "C" void kernel_launch(void* const* d_in, const int* in_sizes, int n_in,
                              void* d_out, int out_size, void* d_ws, size_t ws_size,
                              hipStream_t stream) {
    const float* nodes = (const float*)d_in[0];
    float* out = (float*)d_out;
    (void)in_sizes; (void)n_in; (void)out_size; (void)ws_size;
    float4* pts = (float4*)d_ws;    // 256 KB scratch

    hipLaunchKernelGGL(prep_kernel, dim3(NN / 256), dim3(256), 0, stream,
                       nodes, pts);
    hipLaunchKernelGGL(knn_main, dim3(NN / RPB), dim3(320), 0, stream,
                       pts, out);
}

// Round 12
// 351.361 us; speedup vs baseline: 2.4439x; 1.2068x over previous
//
#include <hip/hip_runtime.h>
#include <math.h>

#define NN 16384
#define KK 16
#define RPW 4                       // rows per scan wave
#define SW 4                        // scan waves per block
#define RPB (SW * RPW)              // 16 rows per block
#define CAP 128                     // per-row candidate buffer

typedef float f32x4 __attribute__((ext_vector_type(4)));
typedef unsigned long long u64;

// ---------- pack nodes into SoA float4 {x,y,z,sq} (reference arithmetic) ----
__global__ void prep_kernel(const float* __restrict__ nodes,
                            float4* __restrict__ pts) {
#pragma clang fp contract(off)
    const int i = blockIdx.x * blockDim.x + threadIdx.x;
    if (i < NN) {
        const float x = nodes[3 * i + 0];
        const float y = nodes[3 * i + 1];
        const float z = nodes[3 * i + 2];
        pts[i] = make_float4(x, y, z, (x * x + y * y) + z * z);
    }
}

__device__ __forceinline__ float bcastf(float v, int l) {
    return __int_as_float(__builtin_amdgcn_readlane(__float_as_int(v), l));
}

// Verified distributed-sorted-list insert (r1-r6) — overflow fallback only.
__device__ __forceinline__ bool lexless(float da, int ia, float db, int ib) {
    return (da < db) || ((da == db) && (ia < ib));
}

__device__ __forceinline__ void insert_tile(bool rough, float d2, int j,
                                            float& ld, int& li,
                                            float& td, int& ti, float& td2u,
                                            int lane) {
#pragma clang fp contract(off)
    if (!__any(rough)) return;
    float dist = INFINITY;
    if (rough) dist = sqrtf(fmaxf(d2, 0.0f));
    bool done = false;
    while (true) {
        const bool pass = (!done) && rough && lexless(dist, j, td, ti);
        const u64 m = __ballot(pass);
        if (m == 0ull) break;
        const int src = __ffsll(m) - 1;
        const float dc = __shfl(dist, src);
        const int   ic = __shfl(j, src);
        if (lane == src) done = true;
        const bool gt = lexless(dc, ic, ld, li);
        const u64 gm = __ballot(gt);
        const int p = __ffsll(gm) - 1;
        const float pd = __shfl_up(ld, 1);
        const int   pi = __shfl_up(li, 1);
        if (gt) {
            if (lane == p) { ld = dc; li = ic; }
            else           { ld = pd; li = pi; }
        }
        td = __shfl(ld, 16);
        ti = __shfl(li, 16);
        td2u = td * td * 1.000001f;
    }
}

// ---------- main kernel: 4 scan waves (4 rows each) + 1 zero/ones wave ------
__global__ __launch_bounds__(320) void knn_main(const float4* __restrict__ pts,
                                                float* __restrict__ out) {
#pragma clang fp contract(off)
    const int lane = threadIdx.x & 63;
    const int wid  = threadIdx.x >> 6;
    const int rowBase = blockIdx.x * RPB;

    __shared__ u64 buf[SW][RPW][CAP];   // 16 KB candidate keys (cd2, idx)
    __shared__ int cnt[SW][RPW];
    __shared__ int nb[RPB][KK];

    if (wid == SW) {
        // Fill wave: NT-stream zeros for this block's 16 rows (1 MB).
        f32x4* ob = (f32x4*)(out + (size_t)rowBase * NN);
        const f32x4 z4 = {0.f, 0.f, 0.f, 0.f};
#pragma unroll 8
        for (int k = 0; k < RPB * (NN / 4) / 64; ++k)
            __builtin_nontemporal_store(z4, ob + k * 64 + lane);
        // Drain so this wave's later 1.0 stores are ordered after the zeros.
        asm volatile("s_waitcnt vmcnt(0)" ::: "memory");
    } else {
        const int r0 = rowBase + wid * RPW;
        float xs[RPW], ys[RPW], zs[RPW], ss[RPW];
#pragma unroll
        for (int r = 0; r < RPW; ++r) {
            const float4 p = pts[r0 + r];
            xs[r] = p.x; ys[r] = p.y; zs[r] = p.z; ss[r] = p.w;
        }

        // ================= PASS A: per-lane min of raw d2 =================
        float rm[RPW];
#pragma unroll
        for (int r = 0; r < RPW; ++r) rm[r] = INFINITY;
        {
            float4 q0 = pts[lane];
            float4 q1 = pts[64 + lane];
            float4 q2 = pts[128 + lane];
            float4 q3 = pts[192 + lane];
            for (int t = 0; t < NN / 256; ++t) {
                const int nxt = (t + 1 < NN / 256) ? (t + 1) * 256 : t * 256;
                const float4 n0 = pts[nxt + lane];
                const float4 n1 = pts[nxt + 64 + lane];
                const float4 n2 = pts[nxt + 128 + lane];
                const float4 n3 = pts[nxt + 192 + lane];
#pragma unroll
                for (int r = 0; r < RPW; ++r) {
                    // Reference arithmetic: fma-chain dot, un-contracted d2.
                    const float d0 = (ss[r] + q0.w) - 2.0f * fmaf(zs[r], q0.z, fmaf(ys[r], q0.y, xs[r] * q0.x));
                    const float d1 = (ss[r] + q1.w) - 2.0f * fmaf(zs[r], q1.z, fmaf(ys[r], q1.y, xs[r] * q1.x));
                    const float d2 = (ss[r] + q2.w) - 2.0f * fmaf(zs[r], q2.z, fmaf(ys[r], q2.y, xs[r] * q2.x));
                    const float d3 = (ss[r] + q3.w) - 2.0f * fmaf(zs[r], q3.z, fmaf(ys[r], q3.y, xs[r] * q3.x));
                    rm[r] = fminf(rm[r], fminf(fminf(d0, d1), fminf(d2, d3)));
                }
                q0 = n0; q1 = n1; q2 = n2; q3 = n3;
            }
        }

        // ====== bitonic sort of 64 lane-mins (ascending); tau = 17th ======
        // Lane-mins are 64 DISTINCT candidates' d2 values, so the 17th
        // smallest lane-min >= the true 17th-smallest d2: conservative.
        float sv[RPW];
#pragma unroll
        for (int r = 0; r < RPW; ++r) sv[r] = rm[r];
#pragma unroll
        for (int k = 2; k <= 64; k <<= 1) {
#pragma unroll
            for (int j = k >> 1; j >= 1; j >>= 1) {
                const bool keepmin = (((lane & j) == 0) == ((lane & k) == 0));
#pragma unroll
                for (int r = 0; r < RPW; ++r) {
                    const float o = __shfl_xor(sv[r], j);
                    sv[r] = keepmin ? fminf(sv[r], o) : fmaxf(sv[r], o);
                }
            }
        }
        float tau[RPW];
#pragma unroll
        for (int r = 0; r < RPW; ++r)   // *1.000002+eps: sqrt-tie-collapse guard
            tau[r] = fmaxf(bcastf(sv[r], 16), 0.0f) * 1.000002f + 1e-30f;

        if (lane < RPW) cnt[wid][lane] = 0;
        asm volatile("s_waitcnt lgkmcnt(0)" ::: "memory");

        // ============ PASS B: screen vs fixed tau, atomic append ============
        {
            float4 q0 = pts[lane];
            float4 q1 = pts[64 + lane];
            float4 q2 = pts[128 + lane];
            float4 q3 = pts[192 + lane];
            for (int t = 0; t < NN / 256; ++t) {
                const int base = t * 256;
                const int nxt = (t + 1 < NN / 256) ? base + 256 : base;
                const float4 n0 = pts[nxt + lane];
                const float4 n1 = pts[nxt + 64 + lane];
                const float4 n2 = pts[nxt + 128 + lane];
                const float4 n3 = pts[nxt + 192 + lane];
#pragma unroll
                for (int r = 0; r < RPW; ++r) {
                    const float d0 = (ss[r] + q0.w) - 2.0f * fmaf(zs[r], q0.z, fmaf(ys[r], q0.y, xs[r] * q0.x));
                    const float d1 = (ss[r] + q1.w) - 2.0f * fmaf(zs[r], q1.z, fmaf(ys[r], q1.y, xs[r] * q1.x));
                    const float d2 = (ss[r] + q2.w) - 2.0f * fmaf(zs[r], q2.z, fmaf(ys[r], q2.y, xs[r] * q2.x));
                    const float d3 = (ss[r] + q3.w) - 2.0f * fmaf(zs[r], q3.z, fmaf(ys[r], q3.y, xs[r] * q3.x));
                    const bool p0 = d0 <= tau[r], p1 = d1 <= tau[r];
                    const bool p2 = d2 <= tau[r], p3 = d3 <= tau[r];
                    if (p0 | p1 | p2 | p3) {
                        if (p0) { const int o = atomicAdd(&cnt[wid][r], 1);
                                  if (o < CAP) buf[wid][r][o] = (((u64)__float_as_uint(fmaxf(d0, 0.f))) << 32) | (unsigned)(base + lane); }
                        if (p1) { const int o = atomicAdd(&cnt[wid][r], 1);
                                  if (o < CAP) buf[wid][r][o] = (((u64)__float_as_uint(fmaxf(d1, 0.f))) << 32) | (unsigned)(base + 64 + lane); }
                        if (p2) { const int o = atomicAdd(&cnt[wid][r], 1);
                                  if (o < CAP) buf[wid][r][o] = (((u64)__float_as_uint(fmaxf(d2, 0.f))) << 32) | (unsigned)(base + 128 + lane); }
                        if (p3) { const int o = atomicAdd(&cnt[wid][r], 1);
                                  if (o < CAP) buf[wid][r][o] = (((u64)__float_as_uint(fmaxf(d3, 0.f))) << 32) | (unsigned)(base + 192 + lane); }
                    }
                }
                q0 = n0; q1 = n1; q2 = n2; q3 = n3;
            }
        }
        asm volatile("s_waitcnt lgkmcnt(0)" ::: "memory");

        // ============ exact lex-(dist,idx) rank among C candidates ============
#pragma unroll
        for (int r = 0; r < RPW; ++r) {
            const int C = cnt[wid][r];          // wave-uniform
            const int rowl = wid * RPW + r;
            if (C <= CAP) {                     // C >= 17 guaranteed by tau
                for (int e = lane; e < C; e += 64) {
                    const u64 k2 = buf[wid][r][e];
                    const float dd = sqrtf(__uint_as_float((unsigned)(k2 >> 32)));
                    buf[wid][r][e] = (((u64)__float_as_uint(dd)) << 32) | (k2 & 0xffffffffull);
                }
                asm volatile("s_waitcnt lgkmcnt(0)" ::: "memory");
                for (int e = lane; e < C; e += 64) {
                    const u64 my = buf[wid][r][e];
                    int rk = 0;
                    for (int c = 0; c < C; ++c)
                        rk += (buf[wid][r][c] < my) ? 1 : 0;   // idx unique => no key ties
                    if (rk >= 1 && rk <= KK)
                        nb[rowl][rk - 1] = (int)(my & 0xffffffffu);  // rank 0 = lex-min, dropped
                }
            } else {
                // Pathological overflow: verified streaming insert for this row.
                float ld = INFINITY; int li = 0x7fffffff;
                float td = INFINITY; int ti = 0x7fffffff; float t2 = INFINITY;
                for (int tt = 0; tt < NN / 64; ++tt) {
                    const int j = tt * 64 + lane;
                    const float4 q = pts[j];
                    const float dd = (ss[r] + q.w) - 2.0f * fmaf(zs[r], q.z, fmaf(ys[r], q.y, xs[r] * q.x));
                    insert_tile(dd <= t2, dd, j, ld, li, td, ti, t2, lane);
                }
                if (lane >= 1 && lane <= KK) nb[rowl][lane - 1] = li;
            }
        }
    }

    __syncthreads();

    // Fill wave writes all 256 ones (16 rows x 16), ordered after its own
    // drained zero stores (same-wave ordering, r6-verified pattern).
    if (wid == SW) {
#pragma unroll
        for (int m = lane; m < RPB * KK; m += 64) {
            const int r = m >> 4;
            out[(size_t)(rowBase + r) * NN + nb[r][m & 15]] = 1.0f;
        }
    }
}

extern "C" void kernel_launch(void* const* d_in, const int* in_sizes, int n_in,
                              void* d_out, int out_size, void* d_ws, size_t ws_size,
                              hipStream_t stream) {
    const float* nodes = (const float*)d_in[0];
    float* out = (float*)d_out;
    (void)in_sizes; (void)n_in; (void)out_size; (void)ws_size;
    float4* pts = (float4*)d_ws;    // 256 KB scratch

    hipLaunchKernelGGL(prep_kernel, dim3(NN / 256), dim3(256), 0, stream,
                       nodes, pts);
    hipLaunchKernelGGL(knn_main, dim3(NN / RPB), dim3(320), 0, stream,
                       pts, out);
}